// Round 5
// baseline (192.297 us; speedup 1.0000x reference)
//
#include <hip/hip_runtime.h>
#include <math.h>

// CrossDomainBridge — MI355X split-bf16 MFMA mega-kernel (round 5).
//
// Math shortcut (exact): softmax rows sum to 1 => corr == 1/2048, dw == 1/8,
// corr_mean == 1/2048; gate bias folds: bg_eff = bg + (1/2048)*sum(Wg[128:131]).
//
// Round-4 lesson: per-lane scalar global stores in MFMA C-layout wrote 64B
// partial lines -> 2x write amplification + read-allocate fetches (~40MB of
// FETCH). Fix: enh reconstructed from the split LDS planes and stored as
// full-line float4 rows; out staged through fp32 LDS (aliased over dead
// xh/ah space) then full-line stores. Plus depth-1 B-frag prefetch in the
// 4-kc GEMM phases. Weights pre-packed in d_ws (needs >= 655360 B).
//
// d_out layout (floats): out[2097152] corr[72] dw[24] enh0 enh1 enh2

typedef __attribute__((ext_vector_type(8))) short short8;
typedef __attribute__((ext_vector_type(4))) float f32x4;
#define MFMA(a, b, c) __builtin_amdgcn_mfma_f32_16x16x32_bf16(a, b, c, 0, 0, 0)

#define NTOK 32

// ws layout (elems, bf16): each matrix [hi S][lo S]
#define WD0_B 0u
#define WD1_B 32768u
#define WD2_B 65536u
#define WT_B  98304u
#define WG_B  163840u
#define WF0_B 196608u
#define WF1_B 229376u
#define WF2_B 262144u
#define WDF_B 294912u

__device__ __forceinline__ unsigned short bf16rtn(float v) {
    unsigned u = __float_as_uint(v);
    unsigned r = u + 0x7FFFu + ((u >> 16) & 1u);
    return (unsigned short)(r >> 16);
}
__device__ __forceinline__ void split2(float v, unsigned short& h, unsigned short& l) {
    h = bf16rtn(v);
    float hf = __uint_as_float(((unsigned)h) << 16);
    l = bf16rtn(v - hf);
}
__device__ __forceinline__ float bf2f(unsigned short h) {
    return __uint_as_float(((unsigned)h) << 16);
}

// Pack weights into fragment-linear split-bf16: for matrix W[K][N], frag
// (nt,kc): lane holds W[kc*32+(lane>>4)*8 + j][nt*16+(lane&15)], j=0..7.
__global__ __launch_bounds__(256) void prep_kernel(
    const float* __restrict__ Ws, const float* __restrict__ Wf,
    const float* __restrict__ Ww, const float* __restrict__ Wt,
    const float* __restrict__ Wg, const float* __restrict__ Wfu,
    const float* __restrict__ Wdf, unsigned short* __restrict__ ws)
{
    int s = blockIdx.x * 256 + threadIdx.x;   // 0..20479 frag-lane slots
    const float* src; int K, N; unsigned base, S; int fi;
    if (s < 2048)      { src = Ws;            K = 64;  N = 256; base = WD0_B; S = 16384; fi = s; }
    else if (s < 4096) { src = Wf;            K = 64;  N = 256; base = WD1_B; S = 16384; fi = s - 2048; }
    else if (s < 6144) { src = Ww;            K = 64;  N = 256; base = WD2_B; S = 16384; fi = s - 4096; }
    else if (s < 10240){ src = Wt;            K = 256; N = 128; base = WT_B;  S = 32768; fi = s - 6144; }
    else if (s < 12288){ src = Wg;            K = 128; N = 128; base = WG_B;  S = 16384; fi = s - 10240; }
    else if (s < 14336){ src = Wfu;           K = 128; N = 128; base = WF0_B; S = 16384; fi = s - 12288; }
    else if (s < 16384){ src = Wfu + 16384;   K = 128; N = 128; base = WF1_B; S = 16384; fi = s - 14336; }
    else if (s < 18432){ src = Wfu + 32768;   K = 128; N = 128; base = WF2_B; S = 16384; fi = s - 16384; }
    else               { src = Wdf;           K = 128; N = 128; base = WDF_B; S = 16384; fi = s - 18432; }
    const int lane = fi & 63, frag = fi >> 6;
    const int KC = K >> 5;
    const int nt = frag / KC, kc = frag - nt * KC;
    const int n  = nt * 16 + (lane & 15);
    const int k0 = kc * 32 + (lane >> 4) * 8;
    short8 hv, lv;
    #pragma unroll
    for (int j = 0; j < 8; ++j) {
        unsigned short h, l;
        split2(src[(k0 + j) * N + n], h, l);
        hv[j] = (short)h; lv[j] = (short)l;
    }
    *(short8*)&ws[base + (unsigned)fi * 8]     = hv;
    *(short8*)&ws[base + S + (unsigned)fi * 8] = lv;
}

// 128-col, K=128 split-bf16 GEMM phase with depth-1 B prefetch.
// A planes Ph/Pl pitch 136; B at wsB (hi), wsB+S (lo).
__device__ __forceinline__ void gemm128(
    const unsigned short* __restrict__ wsB, unsigned S,
    const unsigned short* __restrict__ Ph, const unsigned short* __restrict__ Pl,
    int tokA, int quad, int wn, int lane, f32x4 acc[2])
{
    short8 Bh[2], Bl[2], Bh2[2], Bl2[2];
    #pragma unroll
    for (int i = 0; i < 2; ++i) {
        const unsigned short* bp = wsB + ((unsigned)((wn * 2 + i) * 4) * 64 + lane) * 8;
        Bh[i] = *(const short8*)bp; Bl[i] = *(const short8*)(bp + S);
    }
    #pragma unroll 1
    for (int kc = 0; kc < 4; ++kc) {
        if (kc < 3) {
            #pragma unroll
            for (int i = 0; i < 2; ++i) {
                const unsigned short* bp = wsB + ((unsigned)((wn * 2 + i) * 4 + kc + 1) * 64 + lane) * 8;
                Bh2[i] = *(const short8*)bp; Bl2[i] = *(const short8*)(bp + S);
            }
        }
        const int k = kc * 32 + quad * 8;
        const short8 Ah = *(const short8*)&Ph[tokA * 136 + k];
        const short8 Al = *(const short8*)&Pl[tokA * 136 + k];
        #pragma unroll
        for (int i = 0; i < 2; ++i) {
            acc[i] = MFMA(Ah, Bh[i], acc[i]);
            acc[i] = MFMA(Al, Bh[i], acc[i]);
            acc[i] = MFMA(Ah, Bl[i], acc[i]);
        }
        #pragma unroll
        for (int i = 0; i < 2; ++i) { Bh[i] = Bh2[i]; Bl[i] = Bl2[i]; }
    }
}

__global__ __launch_bounds__(512, 4) void mega_kernel(
    const float* __restrict__ x0, const float* __restrict__ x1,
    const float* __restrict__ x2,
    const float* __restrict__ bd0, const float* __restrict__ bd1,
    const float* __restrict__ bd2,
    const float* __restrict__ g1, const float* __restrict__ b1,
    const float* __restrict__ bt, const float* __restrict__ Wg,
    const float* __restrict__ bg, const float* __restrict__ bfu,
    const float* __restrict__ bdf, const float* __restrict__ g2,
    const float* __restrict__ b2,
    const unsigned short* __restrict__ ws,
    float* __restrict__ out, float* __restrict__ consts,
    float* __restrict__ e0, float* __restrict__ e1, float* __restrict__ e2)
{
    // Manual LDS carve (61440 B): split bf16 activation planes + fp32 out-stage
    __shared__ __align__(16) unsigned char smem[61440];
    unsigned short* xh = (unsigned short*)smem;        // [32][72]
    unsigned short* xl = xh + 32 * 72;
    unsigned short* ah = xl + 32 * 72;                 // [32][264]
    unsigned short* al = ah + 32 * 264;
    unsigned short* th = al + 32 * 264;                // [32][136] (t -> enh -> fused)
    unsigned short* tl = th + 32 * 136;
    float* psum   = (float*)(tl + 32 * 136);           // [32][8]
    float* ostage = (float*)smem;                      // [32][128] fp32, aliases xh/ah (dead at epilogue)

    const int tid = threadIdx.x, wave = tid >> 6, lane = tid & 63;
    const int lm = lane & 15, quad = lane >> 4;
    const int wn = wave & 3, wm = wave >> 2;     // 4 n-groups x 2 m-groups
    const int row0 = blockIdx.x * NTOK;

    if (blockIdx.x == 0) {
        if (tid < 72) consts[tid] = 4.8828125e-4f;      // corr = 1/2048
        else if (tid < 96) consts[tid] = 0.125f;        // dw = 1/8
    }

    // per-lane column sets + cached params
    int cA[4]; float g1c[4], b1c[4];
    #pragma unroll
    for (int i = 0; i < 4; ++i) { cA[i] = (wn * 4 + i) * 16 + lm; g1c[i] = g1[cA[i]]; b1c[i] = b1[cA[i]]; }
    int cT[2]; float btc[2], bgc[2], bdc[2], g2c[2], b2c[2];
    f32x4 facc[2];
    #pragma unroll
    for (int i = 0; i < 2; ++i) {
        const int c = (wn * 2 + i) * 16 + lm; cT[i] = c;
        btc[i] = bt[c];
        bgc[i] = bg[c] + 4.8828125e-4f * (Wg[16384 + c] + Wg[16512 + c] + Wg[16640 + c]);
        bdc[i] = bdf[c]; g2c[i] = g2[c]; b2c[i] = b2[c];
        const float bv = bfu[c];
        facc[i] = (f32x4){bv, bv, bv, bv};
    }

    const float* xs[3]  = {x0, x1, x2};
    const float* bds[3] = {bd0, bd1, bd2};
    float* es[3] = {e0, e1, e2};
    const unsigned WDB[3] = {WD0_B, WD1_B, WD2_B};
    const unsigned WFB[3] = {WF0_B, WF1_B, WF2_B};

    const int tokA = wm * 16 + lm;          // A-frag token for this lane

    for (int d = 0; d < 3; ++d) {
        __syncthreads();                    // prev-domain plane readers done
        {   // stage x split: 1 float4 per thread
            const int tok = tid >> 4, c4 = (tid & 15) * 4;
            const float4 v = *(const float4*)&xs[d][(row0 + tok) * 64 + c4];
            unsigned short h0, l0, h1, l1, h2, l2, h3, l3;
            split2(v.x, h0, l0); split2(v.y, h1, l1);
            split2(v.z, h2, l2); split2(v.w, h3, l3);
            *(ushort4*)&xh[tok * 72 + c4] = make_ushort4(h0, h1, h2, h3);
            *(ushort4*)&xl[tok * 72 + c4] = make_ushort4(l0, l1, l2, l3);
        }
        __syncthreads();

        // ---- Phase A: a_raw = x @ Wd + bd  (2 kc, 4 ntiles/wave) ----
        f32x4 acc[4];
        {
            const float* bdp = bds[d];
            #pragma unroll
            for (int i = 0; i < 4; ++i) { const float bv = bdp[cA[i]]; acc[i] = (f32x4){bv, bv, bv, bv}; }
        }
        #pragma unroll
        for (int kc = 0; kc < 2; ++kc) {
            const int k = kc * 32 + quad * 8;
            const short8 Ah = *(const short8*)&xh[tokA * 72 + k];
            const short8 Al = *(const short8*)&xl[tokA * 72 + k];
            #pragma unroll
            for (int i = 0; i < 4; ++i) {
                const unsigned short* bp = ws + WDB[d] + ((unsigned)((wn * 4 + i) * 2 + kc) * 64 + lane) * 8;
                const short8 Bh = *(const short8*)bp;
                const short8 Bl = *(const short8*)(bp + 16384);
                acc[i] = MFMA(Ah, Bh, acc[i]);
                acc[i] = MFMA(Al, Bh, acc[i]);
                acc[i] = MFMA(Ah, Bl, acc[i]);
            }
        }
        // LN stats from C-layout regs: rows wm*16+quad*4+r, cols cA[i]
        {
            float s[4], qq[4];
            #pragma unroll
            for (int r = 0; r < 4; ++r) {
                s[r] = 0.f; qq[r] = 0.f;
                #pragma unroll
                for (int i = 0; i < 4; ++i) { const float v = acc[i][r]; s[r] += v; qq[r] += v * v; }
            }
            #pragma unroll
            for (int off = 1; off < 16; off <<= 1) {
                #pragma unroll
                for (int r = 0; r < 4; ++r) { s[r] += __shfl_xor(s[r], off); qq[r] += __shfl_xor(qq[r], off); }
            }
            if (lm == 0) {
                #pragma unroll
                for (int r = 0; r < 4; ++r) {
                    const int row = wm * 16 + quad * 4 + r;
                    psum[row * 8 + wn * 2]     = s[r];
                    psum[row * 8 + wn * 2 + 1] = qq[r];
                }
            }
        }
        __syncthreads();
        // normalize + split-store a
        #pragma unroll
        for (int r = 0; r < 4; ++r) {
            const int row = wm * 16 + quad * 4 + r;
            float S = 0.f, Q = 0.f;
            #pragma unroll
            for (int w = 0; w < 4; ++w) { S += psum[row * 8 + w * 2]; Q += psum[row * 8 + w * 2 + 1]; }
            const float m  = S * (1.f / 256.f);
            const float rs = rsqrtf(Q * (1.f / 256.f) - m * m + 1e-3f);
            #pragma unroll
            for (int i = 0; i < 4; ++i) {
                const float v = (acc[i][r] - m) * rs * g1c[i] + b1c[i];
                unsigned short h, l; split2(v, h, l);
                ah[row * 264 + cA[i]] = h; al[row * 264 + cA[i]] = l;
            }
        }
        __syncthreads();

        // ---- Phase T: t = a @ Wt + bt (8 kc, 2 ntiles/wave, B prefetched) ----
        f32x4 tac[2];
        #pragma unroll
        for (int i = 0; i < 2; ++i) tac[i] = (f32x4){btc[i], btc[i], btc[i], btc[i]};
        {
            short8 Bh[2], Bl[2], Bh2[2], Bl2[2];
            #pragma unroll
            for (int i = 0; i < 2; ++i) {
                const unsigned short* bp = ws + WT_B + ((unsigned)((wn * 2 + i) * 8) * 64 + lane) * 8;
                Bh[i] = *(const short8*)bp; Bl[i] = *(const short8*)(bp + 32768);
            }
            #pragma unroll 1
            for (int kc = 0; kc < 8; ++kc) {
                if (kc < 7) {
                    #pragma unroll
                    for (int i = 0; i < 2; ++i) {
                        const unsigned short* bp = ws + WT_B + ((unsigned)((wn * 2 + i) * 8 + kc + 1) * 64 + lane) * 8;
                        Bh2[i] = *(const short8*)bp; Bl2[i] = *(const short8*)(bp + 32768);
                    }
                }
                const int k = kc * 32 + quad * 8;
                const short8 Ah = *(const short8*)&ah[tokA * 264 + k];
                const short8 Al = *(const short8*)&al[tokA * 264 + k];
                #pragma unroll
                for (int i = 0; i < 2; ++i) {
                    tac[i] = MFMA(Ah, Bh[i], tac[i]);
                    tac[i] = MFMA(Al, Bh[i], tac[i]);
                    tac[i] = MFMA(Ah, Bl[i], tac[i]);
                }
                #pragma unroll
                for (int i = 0; i < 2; ++i) { Bh[i] = Bh2[i]; Bl[i] = Bl2[i]; }
            }
        }
        // t -> split planes
        #pragma unroll
        for (int i = 0; i < 2; ++i)
            #pragma unroll
            for (int r = 0; r < 4; ++r) {
                const int row = wm * 16 + quad * 4 + r;
                unsigned short h, l; split2(tac[i][r], h, l);
                th[row * 136 + cT[i]] = h; tl[row * 136 + cT[i]] = l;
            }
        __syncthreads();

        // ---- Phase G: z = t @ Wg0 + bg_eff ----
        f32x4 zac[2];
        #pragma unroll
        for (int i = 0; i < 2; ++i) zac[i] = (f32x4){bgc[i], bgc[i], bgc[i], bgc[i]};
        gemm128(ws + WG_B, 16384, th, tl, tokA, quad, wn, lane, zac);

        // enh = t * sigmoid(z) * 0.125  (t read from planes)
        float er[2][4];
        #pragma unroll
        for (int i = 0; i < 2; ++i)
            #pragma unroll
            for (int r = 0; r < 4; ++r) {
                const int row = wm * 16 + quad * 4 + r;
                const float tv = bf2f(th[row * 136 + cT[i]]) + bf2f(tl[row * 136 + cT[i]]);
                er[i][r] = tv * (1.f / (1.f + __expf(-zac[i][r]))) * 0.125f;
            }
        __syncthreads();                    // all t reads done before overwrite
        #pragma unroll
        for (int i = 0; i < 2; ++i)
            #pragma unroll
            for (int r = 0; r < 4; ++r) {
                const int row = wm * 16 + quad * 4 + r;
                unsigned short h, l; split2(er[i][r], h, l);
                th[row * 136 + cT[i]] = h; tl[row * 136 + cT[i]] = l;
            }
        __syncthreads();

        // coalesced enh store from planes: full 128B lines
        {
            const int row = tid >> 4, c8 = (tid & 15) * 8;
            const ushort4 h0 = *(const ushort4*)&th[row * 136 + c8];
            const ushort4 h1 = *(const ushort4*)&th[row * 136 + c8 + 4];
            const ushort4 l0 = *(const ushort4*)&tl[row * 136 + c8];
            const ushort4 l1 = *(const ushort4*)&tl[row * 136 + c8 + 4];
            float* ep = es[d] + (row0 + row) * 128 + c8;
            *(float4*)ep = make_float4(bf2f(h0.x) + bf2f(l0.x), bf2f(h0.y) + bf2f(l0.y),
                                       bf2f(h0.z) + bf2f(l0.z), bf2f(h0.w) + bf2f(l0.w));
            *(float4*)(ep + 4) = make_float4(bf2f(h1.x) + bf2f(l1.x), bf2f(h1.y) + bf2f(l1.y),
                                             bf2f(h1.z) + bf2f(l1.z), bf2f(h1.w) + bf2f(l1.w));
        }

        // ---- Fuse acc: facc += enh_d @ Wfu_d ----
        gemm128(ws + WFB[d], 16384, th, tl, tokA, quad, wn, lane, facc);
    }

    __syncthreads();
    // fused -> split planes
    #pragma unroll
    for (int i = 0; i < 2; ++i)
        #pragma unroll
        for (int r = 0; r < 4; ++r) {
            const int row = wm * 16 + quad * 4 + r;
            unsigned short h, l; split2(facc[i][r], h, l);
            th[row * 136 + cT[i]] = h; tl[row * 136 + cT[i]] = l;
        }
    __syncthreads();

    // ---- df = fused @ Wdf + bdf ----
    f32x4 dac[2];
    #pragma unroll
    for (int i = 0; i < 2; ++i) dac[i] = (f32x4){bdc[i], bdc[i], bdc[i], bdc[i]};
    gemm128(ws + WDF_B, 16384, th, tl, tokA, quad, wn, lane, dac);

    // ---- final LN over 128 ----
    {
        float s[4], qq[4];
        #pragma unroll
        for (int r = 0; r < 4; ++r) {
            s[r] = dac[0][r] + dac[1][r];
            qq[r] = dac[0][r] * dac[0][r] + dac[1][r] * dac[1][r];
        }
        #pragma unroll
        for (int off = 1; off < 16; off <<= 1) {
            #pragma unroll
            for (int r = 0; r < 4; ++r) { s[r] += __shfl_xor(s[r], off); qq[r] += __shfl_xor(qq[r], off); }
        }
        if (lm == 0) {
            #pragma unroll
            for (int r = 0; r < 4; ++r) {
                const int row = wm * 16 + quad * 4 + r;
                psum[row * 8 + wn * 2]     = s[r];
                psum[row * 8 + wn * 2 + 1] = qq[r];
            }
        }
    }
    __syncthreads();
    #pragma unroll
    for (int r = 0; r < 4; ++r) {
        const int row = wm * 16 + quad * 4 + r;
        float S = 0.f, Q = 0.f;
        #pragma unroll
        for (int w = 0; w < 4; ++w) { S += psum[row * 8 + w * 2]; Q += psum[row * 8 + w * 2 + 1]; }
        const float m  = S * (1.f / 128.f);
        const float rs = rsqrtf(Q * (1.f / 128.f) - m * m + 1e-3f);
        #pragma unroll
        for (int i = 0; i < 2; ++i)
            ostage[row * 128 + cT[i]] = (dac[i][r] - m) * rs * g2c[i] + b2c[i];
    }
    __syncthreads();
    {   // coalesced fp32 out store: full 128B lines
        const int row = tid >> 4, c8 = (tid & 15) * 8;
        const float4 o0 = *(const float4*)&ostage[row * 128 + c8];
        const float4 o1 = *(const float4*)&ostage[row * 128 + c8 + 4];
        float* op = out + (row0 + row) * 128 + c8;
        *(float4*)op = o0;
        *(float4*)(op + 4) = o1;
    }
}

extern "C" void kernel_launch(void* const* d_in, const int* in_sizes, int n_in,
                              void* d_out, int out_size, void* d_ws, size_t ws_size,
                              hipStream_t stream) {
    const float* spatial   = (const float*)d_in[0];
    const float* frequency = (const float*)d_in[1];
    const float* wavelet   = (const float*)d_in[2];
    const float* Ws  = (const float*)d_in[3];
    const float* bs  = (const float*)d_in[4];
    const float* Wf  = (const float*)d_in[5];
    const float* bf  = (const float*)d_in[6];
    const float* Ww  = (const float*)d_in[7];
    const float* bw  = (const float*)d_in[8];
    const float* g1  = (const float*)d_in[9];
    const float* b1  = (const float*)d_in[10];
    // d_in[11..14] = Wk, bk, Wq, bq — provably unused (corr is constant)
    const float* Wt  = (const float*)d_in[15];
    const float* bt  = (const float*)d_in[16];
    const float* Wg  = (const float*)d_in[17];
    const float* bg  = (const float*)d_in[18];
    const float* Wfu = (const float*)d_in[19];
    const float* bfu = (const float*)d_in[20];
    const float* Wdf = (const float*)d_in[21];
    const float* bdf = (const float*)d_in[22];
    const float* g2  = (const float*)d_in[23];
    const float* b2  = (const float*)d_in[24];

    float* out    = (float*)d_out;
    float* consts = out + 2097152;          // corr[72] + dw[24]
    float* enh0   = out + 2097248;
    float* enh1   = out + 4194400;
    float* enh2   = out + 6291552;
    unsigned short* wsp = (unsigned short*)d_ws;   // needs 655360 B

    prep_kernel<<<80, 256, 0, stream>>>(Ws, Wf, Ww, Wt, Wg, Wfu, Wdf, wsp);
    mega_kernel<<<16384 / NTOK, 512, 0, stream>>>(
        spatial, frequency, wavelet, bs, bf, bw, g1, b1,
        bt, Wg, bg, bfu, bdf, g2, b2, wsp,
        out, consts, enh0, enh1, enh2);
}